// Round 30
// baseline (57.669 us; speedup 1.0000x reference)
//
#include <hip/hip_runtime.h>
#include <hip/hip_bf16.h>

#define SCOPE 63
#define BT 256
#define RPB 64                      // rows per block

typedef __attribute__((ext_vector_type(8))) __bf16 v8bf;
typedef __attribute__((ext_vector_type(4))) float f32x4;

// async global->LDS, 16B per lane; LDS dest is wave-uniform base + lane*16
#define GLL(gp, lp) __builtin_amdgcn_global_load_lds(                         \
    (const __attribute__((address_space(1))) void*)(gp),                      \
    (__attribute__((address_space(3))) void*)(lp), 16, 0, 0)

// ws layout: [0,256) g as float[63]; [256, 8448) Bhi bf16[4096];
//            [8448, 16640) Blo bf16[4096]   (fragment order [nt][kt][lane][8])
#define WS_BHI_OFF 256
#define WS_BLO_OFF 8448

// ---------------------------------------------------------------------------
// Kernel 1 (one-time): g = IFFT(1/FFT(delta-f)) in fp64 via 63-entry twiddle
// table (r29: ~2 us), + fragment-ordered bf16 hi/lo B arrays into d_ws.
// ---------------------------------------------------------------------------
__global__ void compute_inverse_filter(const float* __restrict__ f,
                                       float* __restrict__ ws) {
    __shared__ double cd[SCOPE];
    __shared__ double sd[SCOPE];
    __shared__ double hre[SCOPE];
    __shared__ double him[SCOPE];
    __shared__ float gsm[SCOPE];
    const double TWO_PI = 6.283185307179586476925286766559;
    int t = threadIdx.x;

    if (t < SCOPE) {
        double ang = -TWO_PI * (double)t / (double)SCOPE;
        cd[t] = cos(ang);
        sd[t] = sin(ang);
    }
    __syncthreads();

    if (t < SCOPE) {
        double re = 0.0, im = 0.0;
        for (int n = 0; n < SCOPE; ++n) {
            double x = (n == 0 ? 1.0 : 0.0) - (double)f[n];
            int m = (t * n) % SCOPE;
            re += x * cd[m];
            im += x * sd[m];
        }
        double d = re * re + im * im;
        hre[t] = re / d;
        him[t] = -im / d;
    }
    __syncthreads();

    if (t < SCOPE) {
        double acc = 0.0;
        for (int k = 0; k < SCOPE; ++k) {
            int m = (k * t) % SCOPE;
            acc += hre[k] * cd[m] + him[k] * sd[m];
        }
        float gv = (float)(acc / (double)SCOPE);
        ws[t] = gv;
        gsm[t] = gv;
    }
    __syncthreads();

    __bf16* Bhi = (__bf16*)((char*)ws + WS_BHI_OFF);
    __bf16* Blo = (__bf16*)((char*)ws + WS_BLO_OFF);
    for (int fidx = t; fidx < 4096; fidx += blockDim.x) {
        const int j  = fidx & 7;
        const int fl = (fidx >> 3) & 63;
        const int kt = (fidx >> 9) & 1;
        const int nt = fidx >> 10;
        const int k  = 8 * (fl >> 4) + j + 32 * kt;
        const int n  = 16 * nt + (fl & 15);
        float v = (k < SCOPE && n < SCOPE) ? gsm[(n - k + SCOPE) % SCOPE] : 0.0f;
        __bf16 h = (__bf16)v;
        Bhi[fidx] = h;
        Blo[fidx] = (__bf16)(v - (float)h);
    }
}

// ---------------------------------------------------------------------------
// Kernel 2: circulant MFMA matmul, r30: PADDED+SWIZZLED A-tile.
//
// LDS: [64 rows][64 floats] = 16384 B. Slot (r, gl) holds global float group
// gk = gl ^ (r&7)  (floats r*63 + 4gk .. +3)  — T2 XOR swizzle baked in at
// staging via PRE-SWIZZLED PER-LANE GLL SOURCE (LDS dest stays linear,
// rule #21). A-frag reads become two ALIGNED ds_read_b128 at
//   r*256 + ((fg ^ (r&7)) << 4),  fg = 8kt + 2q + h
// -> conflict-free (XOR spreads 16 same-col rows over 8 bank-quads) and no
// more 4B-misaligned split loads (r19-r29: 2.1M SQ_LDS_BANK_CONFLICT).
//
// gk=15 slots carry floats 60..63 where float 63 = next row's first element
// (finite, killed by B's k=63 zero row). Only OOB case (last block, r=63)
// filled by a 4-thread fallback with explicit zero pad.
//
// C is written COMPACTLY into the wave's own region [w*4096, +4032)
// (rows rr=4q+i stride 252 B) -> store phase is per-wave linear float4 and
// the second barrier disappears (wave-local DS ordering).
// ---------------------------------------------------------------------------
__global__ void __launch_bounds__(BT)
circ_conv_kernel(const float* __restrict__ A,
                 const float* __restrict__ WS,
                 float* __restrict__ O) {
    __shared__ __align__(16) unsigned char tile[16384 + 16];

    const int tid = threadIdx.x;
    const int w   = tid >> 6;        // wave in block
    const int l   = tid & 63;        // lane in wave
    const int c   = l & 15;          // fragment column index
    const int q   = l >> 4;          // fragment k-group / row-group

    const long long row0 = (long long)blockIdx.x * RPB;
    const float* __restrict__ src = A + row0 * SCOPE;
    float* __restrict__ dst       = O + row0 * SCOPE;

    const bool last = ((int)blockIdx.x == (int)gridDim.x - 1);

    // ---- stage 64 rows, swizzled source -> linear LDS dest (GLL) ----
#pragma unroll
    for (int it = 0; it < 4; ++it) {
        const int i  = it * 256 + tid;   // LDS 16B-group index
        const int r  = i >> 4;
        const int gl = i & 15;
        const int gk = gl ^ (r & 7);     // source float group
        const bool oob = (gk == 15) && last && (r == 63);
        if (!oob)
            GLL(src + r * SCOPE + 4 * gk, tile + i * 16);
    }
    // last-block fallback for slot (r=63, gk=15): floats 60..62 + zero pad
    if (last && tid < 4) {
        const int r = 63, gl = 15 ^ (r & 7);
        float v = (tid < 3) ? src[r * SCOPE + 60 + tid] : 0.0f;
        *(float*)(tile + r * 256 + gl * 16 + tid * 4) = v;
    }

    // ---- B fragments: global ws, identical across blocks -> L2 broadcast ----
    const v8bf* BH = (const v8bf*)((const char*)WS + WS_BHI_OFF);
    const v8bf* BL = (const v8bf*)((const char*)WS + WS_BLO_OFF);
    v8bf bh[4][2], bl[4][2];
#pragma unroll
    for (int nt = 0; nt < 4; ++nt)
#pragma unroll
        for (int kt = 0; kt < 2; ++kt) {
            bh[nt][kt] = BH[(nt * 2 + kt) * 64 + l];
            bl[nt][kt] = BL[(nt * 2 + kt) * 64 + l];
        }

    __syncthreads();   // tile ready (vmcnt + fallback ds_write drained)

    // ---- A fragments: aligned swizzled b128 pairs ----
    const int r  = 16 * w + c;
    const int rx = r & 7;
    v8bf ah[2], al[2];
#pragma unroll
    for (int kt = 0; kt < 2; ++kt) {
        const int fg0 = 8 * kt + 2 * q;
        float4 v0 = *(const float4*)(tile + r * 256 + ((fg0 ^ rx) << 4));
        float4 v1 = *(const float4*)(tile + r * 256 + (((fg0 + 1) ^ rx) << 4));
        float tmp[8] = {v0.x, v0.y, v0.z, v0.w, v1.x, v1.y, v1.z, v1.w};
#pragma unroll
        for (int j = 0; j < 8; ++j) {
            float v = tmp[j];
            __bf16 h = (__bf16)v;
            ah[kt][j] = h;
            al[kt][j] = (__bf16)(v - (float)h);
        }
    }

    // ---- 4 N-tiles x (2 kt x 3 passes) = 24 MFMA; C compact in own region ----
    float* cw = (float*)(tile + w * 4096);   // wave's region: 16 rows x 63 floats
#pragma unroll
    for (int nt = 0; nt < 4; ++nt) {
        f32x4 acc = {0.f, 0.f, 0.f, 0.f};
#pragma unroll
        for (int kt = 0; kt < 2; ++kt) {
            acc = __builtin_amdgcn_mfma_f32_16x16x32_bf16(ah[kt], bh[nt][kt], acc, 0, 0, 0);
            acc = __builtin_amdgcn_mfma_f32_16x16x32_bf16(ah[kt], bl[nt][kt], acc, 0, 0, 0);
            acc = __builtin_amdgcn_mfma_f32_16x16x32_bf16(al[kt], bh[nt][kt], acc, 0, 0, 0);
        }
        const int col = 16 * nt + c;
        if (col < SCOPE) {
            float* cp = cw + (4 * q) * SCOPE + col;   // rows rr = 4q + i
#pragma unroll
            for (int i = 0; i < 4; ++i)
                cp[i * SCOPE] = acc[i];
        }
    }

    // ---- per-wave store: own region, linear float4 (no barrier needed:
    //      wave-local DS ordering; reads only this wave's C writes) ----
    float* wdst = dst + (long long)w * (16 * SCOPE);   // rows 16w..16w+15
#pragma unroll
    for (int it = 0; it < 4; ++it) {
        const int gidx = it * 64 + l;    // 16B group within 4032 B
        if (gidx < 252) {
            float4 v = *(const float4*)(tile + w * 4096 + gidx * 16);
            *(float4*)(wdst + gidx * 4) = v;
        }
    }
}

// ---------------------------------------------------------------------------
extern "C" void kernel_launch(void* const* d_in, const int* in_sizes, int n_in,
                              void* d_out, int out_size, void* d_ws, size_t ws_size,
                              hipStream_t stream) {
    const float* activations = (const float*)d_in[0];
    const float* filt        = (const float*)d_in[1];
    float* out               = (float*)d_out;
    float* ws                = (float*)d_ws;   // g + B-fragment arrays (~17 KB)

    hipLaunchKernelGGL(compute_inverse_filter, dim3(1), dim3(BT), 0, stream,
                       filt, ws);

    const long long total = (long long)in_sizes[0];
    const long long rows  = total / SCOPE;          // 524288
    const int blocks      = (int)(rows / RPB);      // 8192, exact

    hipLaunchKernelGGL(circ_conv_kernel, dim3(blocks), dim3(BT), 0,
                       stream, activations, ws, out);
}